// Round 15
// baseline (41.051 us; speedup 1.0000x reference)
//
#include <hip/hip_runtime.h>
#include <hip/hip_bf16.h>

typedef float    f32x4 __attribute__((ext_vector_type(4)));
typedef _Float16 f16x4 __attribute__((ext_vector_type(4)));
typedef _Float16 f16x8 __attribute__((ext_vector_type(8)));
typedef unsigned int   u32x4 __attribute__((ext_vector_type(4)));

#define NB 32
#define NA 64
#define NF 128
#define NC 128

// ---------------------------------------------------------------------------
// MEASUREMENT ROUND (R15): identical to R14 except prep is launched 4x
// (idempotent). prep_exec ~= (T_R15 - T_R14) / 3. Main unchanged.
// ---------------------------------------------------------------------------
__global__ __launch_bounds__(256) void prep_kernel(
    const float* __restrict__ x, const float* __restrict__ W0,
    const float* __restrict__ b0, const float* __restrict__ W1,
    _Float16* __restrict__ u, _Float16* __restrict__ v,
    _Float16* __restrict__ w1f)
{
    int blk = blockIdx.x, tid = threadIdx.x;
    int lane = tid & 63, wave = tid >> 6;
    int llo = lane & 15, lhi = lane >> 4;

    if (blk < 512) {
        __shared__ __align__(16) _Float16 w0l[4 * 64 * 8];   // 4 KB frag-major
        int b = blk >> 4, half = (blk >> 3) & 1, nq = blk & 7;

        const float* xrow = x + ((size_t)b * NA + wave * 16 + llo) * NF;
        f16x8 xf[4];
        #pragma unroll
        for (int kk = 0; kk < 4; ++kk) {
            f32x4 a0 = *(const f32x4*)(xrow + kk * 32 + lhi * 8);
            f32x4 a1 = *(const f32x4*)(xrow + kk * 32 + lhi * 8 + 4);
            #pragma unroll
            for (int e = 0; e < 4; ++e) {
                xf[kk][e]     = (_Float16)a0[e];
                xf[kk][e + 4] = (_Float16)a1[e];
            }
        }

        {
            int kk = tid >> 6, ln = tid & 63;
            int k0 = half * 128 + kk * 32 + (ln >> 4) * 8;
            int c  = nq * 16 + (ln & 15);
            f16x8 o;
            #pragma unroll
            for (int e = 0; e < 8; ++e)
                o[e] = (_Float16)W0[(size_t)(k0 + e) * NC + c];
            *(f16x8*)(w0l + (size_t)tid * 8) = o;
        }
        __syncthreads();

        f32x4 acc = {0.f, 0.f, 0.f, 0.f};
        #pragma unroll
        for (int kk = 0; kk < 4; ++kk) {
            f16x8 bw = *(const f16x8*)(w0l + (size_t)((kk * 64 + lane)) * 8);
            acc = __builtin_amdgcn_mfma_f32_16x16x32_f16(xf[kk], bw, acc, 0, 0, 0);
        }

        _Float16* dst = half ? v : u;
        int c = nq * 16 + llo;
        float bb = half ? b0[c] : 0.f;
        #pragma unroll
        for (int q = 0; q < 4; ++q) {
            int atom = wave * 16 + lhi * 4 + q;
            dst[((size_t)b * NA + atom) * NC + c] = (_Float16)(acc[q] + bb);
        }
    } else {
        int fl   = (blk - 512) * 256 + tid;   // 0..2047
        int ln   = fl & 63;
        int frag = fl >> 6;                   // kk*8+nf
        int kk = frag >> 3, nf = frag & 7;
        int k0 = kk * 32 + (ln >> 4) * 8;
        int n  = nf * 16 + (ln & 15);
        f16x8 o;
        #pragma unroll
        for (int e = 0; e < 8; ++e)
            o[e] = (_Float16)W1[(size_t)(k0 + e) * NC + n];
        *(f16x8*)(w1f + (size_t)fl * 8) = o;
    }
}

__global__ __launch_bounds__(256, 4) void pair_mlp_kernel(
    const float* __restrict__ b1g, const _Float16* __restrict__ u,
    const _Float16* __restrict__ v, const _Float16* __restrict__ w1f,
    float* __restrict__ out)
{
    __shared__ __align__(16) _Float16 u_s[16 * 128];    // 4 KB
    __shared__ __align__(16) _Float16 v_s[16 * 128];    // 4 KB
    __shared__ __align__(16) _Float16 w_s[32 * 64 * 8]; // 32 KB frag-major

    int blk = blockIdx.x;
    int b = blk / 36;
    int t = blk % 36;
    int I = 0;
    while (t >= 8 - I) { t -= 8 - I; ++I; }
    int J = I + t;

    int tid = threadIdx.x;

    {
        int row = tid >> 4;            // 0..15
        int c   = tid & 15;            // 16B chunk within 256B row
        int ga  = b * NA + ((row < 8) ? (I * 8 + row) : (J * 8 + (row & 7)));
        int sc  = row * 16 + (c ^ (row & 7));
        ((u32x4*)u_s)[sc] = ((const u32x4*)(u + (size_t)ga * NC))[c];
        ((u32x4*)v_s)[sc] = ((const u32x4*)(v + (size_t)ga * NC))[c];
    }
    #pragma unroll
    for (int p = 0; p < 8; ++p)
        ((u32x4*)w_s)[p * 256 + tid] = ((const u32x4*)w1f)[p * 256 + tid];
    __syncthreads();

    int wave = tid >> 6;
    int lane = tid & 63;
    int llo  = lane & 15;
    int lhi  = lane >> 4;
    int r    = wave * 16 + llo;
    int il   = r >> 3;            // 0..7
    int jl   = r & 7;             // 0..7

    f32x4 acc0[8], acc1[8];
    f32x4 z = {0.f, 0.f, 0.f, 0.f};
    #pragma unroll
    for (int nf = 0; nf < 8; ++nf) { acc0[nf] = z; acc1[nf] = z; }

    const f16x8* us = (const f16x8*)u_s;
    const f16x8* vs = (const f16x8*)v_s;
    const f16x8* wf = (const f16x8*)w_s;

    #pragma unroll
    for (int kk = 0; kk < 4; ++kk) {
        int kc  = kk * 4 + lhi;
        int scI = il * 16 + (kc ^ il);          // il&7 == il
        int scJ = (8 + jl) * 16 + (kc ^ jl);    // (8+jl)&7 == jl

        f16x8 uIv = us[scI];
        f16x8 vIv = vs[scI];
        f16x8 uJv = us[scJ];
        f16x8 vJv = vs[scJ];

        f16x8 s0 = uIv + vJv;
        f16x8 s1 = uJv + vIv;
        f16x8 h0, h1;
        #pragma unroll
        for (int e = 0; e < 8; ++e) {
            h0[e] = s0[e] < (_Float16)0 ? (_Float16)0 : s0[e];
            h1[e] = s1[e] < (_Float16)0 ? (_Float16)0 : s1[e];
        }

        #pragma unroll
        for (int nf = 0; nf < 8; ++nf) {
            f16x8 w = wf[(kk * 8 + nf) * 64 + lane];
            acc0[nf] = __builtin_amdgcn_mfma_f32_16x16x32_f16(w, h0, acc0[nf], 0, 0, 0);
            acc1[nf] = __builtin_amdgcn_mfma_f32_16x16x32_f16(w, h1, acc1[nf], 0, 0, 0);
        }
    }

    int Ig = I * 8 + il;
    int Jg = J * 8 + jl;
    float* p1 = out + ((size_t)b * 4096 + Ig * 64 + Jg) * 128 + lhi * 4;
    float* p2 = out + ((size_t)b * 4096 + Jg * 64 + Ig) * 128 + lhi * 4;
    bool mirror = (I != J);
    #pragma unroll
    for (int nf = 0; nf < 8; ++nf) {
        f32x4 bias = *(const f32x4*)(b1g + nf * 16 + lhi * 4);
        f32x4 val;
        #pragma unroll
        for (int e = 0; e < 4; ++e)
            val[e] = fmaxf(acc0[nf][e] + bias[e], 0.f) +
                     fmaxf(acc1[nf][e] + bias[e], 0.f);
        *(f32x4*)(p1 + nf * 16) = val;
        if (mirror)
            *(f32x4*)(p2 + nf * 16) = val;
    }
}

extern "C" void kernel_launch(void* const* d_in, const int* in_sizes, int n_in,
                              void* d_out, int out_size, void* d_ws, size_t ws_size,
                              hipStream_t stream)
{
    (void)in_sizes; (void)n_in; (void)out_size; (void)ws_size;
    const float* x  = (const float*)d_in[0];
    const float* W0 = (const float*)d_in[1];
    const float* b0 = (const float*)d_in[2];
    const float* W1 = (const float*)d_in[3];
    const float* b1 = (const float*)d_in[4];
    float* out = (float*)d_out;

    _Float16* u   = (_Float16*)d_ws;                       // 0.5 MB
    _Float16* v   = u + (size_t)NB * NA * NC;              // 0.5 MB
    _Float16* w1f = v + (size_t)NB * NA * NC;              // 32 KB

    // 4x identical, idempotent prep launches: prep ~= (T_R15 - T_R14) / 3
    prep_kernel<<<520, 256, 0, stream>>>(x, W0, b0, W1, u, v, w1f);
    prep_kernel<<<520, 256, 0, stream>>>(x, W0, b0, W1, u, v, w1f);
    prep_kernel<<<520, 256, 0, stream>>>(x, W0, b0, W1, u, v, w1f);
    prep_kernel<<<520, 256, 0, stream>>>(x, W0, b0, W1, u, v, w1f);
    pair_mlp_kernel<<<32 * 36, 256, 0, stream>>>(b1, u, v, w1f, out);
}

// Round 16
// 39.740 us; speedup vs baseline: 1.0330x; 1.0330x over previous
//
#include <hip/hip_runtime.h>
#include <hip/hip_bf16.h>

typedef float    f32x4 __attribute__((ext_vector_type(4)));
typedef _Float16 f16x4 __attribute__((ext_vector_type(4)));
typedef _Float16 f16x8 __attribute__((ext_vector_type(8)));
typedef unsigned int   u32x4 __attribute__((ext_vector_type(4)));

#define NB 32
#define NA 64
#define NF 128
#define NC 128

// ---------------------------------------------------------------------------
// prep (R13/R14, unchanged — measured 3.8 us incl. boundary):
// blocks 0..511: u/v via latency-parallel f16 MFMA; 512..519: w1f build.
// ---------------------------------------------------------------------------
__global__ __launch_bounds__(256) void prep_kernel(
    const float* __restrict__ x, const float* __restrict__ W0,
    const float* __restrict__ b0, const float* __restrict__ W1,
    _Float16* __restrict__ u, _Float16* __restrict__ v,
    _Float16* __restrict__ w1f)
{
    int blk = blockIdx.x, tid = threadIdx.x;
    int lane = tid & 63, wave = tid >> 6;
    int llo = lane & 15, lhi = lane >> 4;

    if (blk < 512) {
        __shared__ __align__(16) _Float16 w0l[4 * 64 * 8];   // 4 KB frag-major
        int b = blk >> 4, half = (blk >> 3) & 1, nq = blk & 7;

        const float* xrow = x + ((size_t)b * NA + wave * 16 + llo) * NF;
        f16x8 xf[4];
        #pragma unroll
        for (int kk = 0; kk < 4; ++kk) {
            f32x4 a0 = *(const f32x4*)(xrow + kk * 32 + lhi * 8);
            f32x4 a1 = *(const f32x4*)(xrow + kk * 32 + lhi * 8 + 4);
            #pragma unroll
            for (int e = 0; e < 4; ++e) {
                xf[kk][e]     = (_Float16)a0[e];
                xf[kk][e + 4] = (_Float16)a1[e];
            }
        }

        {
            int kk = tid >> 6, ln = tid & 63;
            int k0 = half * 128 + kk * 32 + (ln >> 4) * 8;
            int c  = nq * 16 + (ln & 15);
            f16x8 o;
            #pragma unroll
            for (int e = 0; e < 8; ++e)
                o[e] = (_Float16)W0[(size_t)(k0 + e) * NC + c];
            *(f16x8*)(w0l + (size_t)tid * 8) = o;
        }
        __syncthreads();

        f32x4 acc = {0.f, 0.f, 0.f, 0.f};
        #pragma unroll
        for (int kk = 0; kk < 4; ++kk) {
            f16x8 bw = *(const f16x8*)(w0l + (size_t)((kk * 64 + lane)) * 8);
            acc = __builtin_amdgcn_mfma_f32_16x16x32_f16(xf[kk], bw, acc, 0, 0, 0);
        }

        _Float16* dst = half ? v : u;
        int c = nq * 16 + llo;
        float bb = half ? b0[c] : 0.f;
        #pragma unroll
        for (int q = 0; q < 4; ++q) {
            int atom = wave * 16 + lhi * 4 + q;
            dst[((size_t)b * NA + atom) * NC + c] = (_Float16)(acc[q] + bb);
        }
    } else {
        int fl   = (blk - 512) * 256 + tid;   // 0..2047
        int ln   = fl & 63;
        int frag = fl >> 6;                   // kk*8+nf
        int kk = frag >> 3, nf = frag & 7;
        int k0 = kk * 32 + (ln >> 4) * 8;
        int n  = nf * 16 + (ln & 15);
        f16x8 o;
        #pragma unroll
        for (int e = 0; e < 8; ++e)
            o[e] = (_Float16)W1[(size_t)(k0 + e) * NC + n];
        *(f16x8*)(w1f + (size_t)fl * 8) = o;
    }
}

// ---------------------------------------------------------------------------
// main: R14 body, but 576 blocks x 2 tasks (same batch). w_s (32 KB) staged
// ONCE per block -> halves the dominant staging; halves dispatch count.
// ---------------------------------------------------------------------------
__global__ __launch_bounds__(256, 4) void pair_mlp_kernel(
    const float* __restrict__ b1g, const _Float16* __restrict__ u,
    const _Float16* __restrict__ v, const _Float16* __restrict__ w1f,
    float* __restrict__ out)
{
    __shared__ __align__(16) _Float16 u_s[16 * 128];    // 4 KB
    __shared__ __align__(16) _Float16 v_s[16 * 128];    // 4 KB
    __shared__ __align__(16) _Float16 w_s[32 * 64 * 8]; // 32 KB frag-major

    int blk = blockIdx.x, tid = threadIdx.x;
    int wave = tid >> 6, lane = tid & 63;
    int llo  = lane & 15, lhi = lane >> 4;
    f32x4 z = {0.f, 0.f, 0.f, 0.f};

    // ---- stage W1 frags once per block
    #pragma unroll
    for (int p = 0; p < 8; ++p)
        ((u32x4*)w_s)[p * 256 + tid] = ((const u32x4*)w1f)[p * 256 + tid];

    #pragma unroll 1
    for (int s = 0; s < 2; ++s) {
        int task = blk * 2 + s;           // 0..1151 (same b for s=0,1)
        int b = task / 36;
        int t = task % 36;
        int I = 0;
        while (t >= 8 - I) { t -= 8 - I; ++I; }
        int J = I + t;

        if (s) __syncthreads();           // prev task's u_s/v_s readers done

        // ---- stage u/v tiles, swizzled: chunk = row*16 + (c ^ (row&7))
        {
            int row = tid >> 4;           // 0..15
            int c   = tid & 15;           // 16B chunk within 256B row
            int ga  = b * NA + ((row < 8) ? (I * 8 + row) : (J * 8 + (row & 7)));
            int sc  = row * 16 + (c ^ (row & 7));
            ((u32x4*)u_s)[sc] = ((const u32x4*)(u + (size_t)ga * NC))[c];
            ((u32x4*)v_s)[sc] = ((const u32x4*)(v + (size_t)ga * NC))[c];
        }
        __syncthreads();

        int r  = wave * 16 + llo;
        int il = r >> 3;                  // 0..7
        int jl = r & 7;                   // 0..7

        f32x4 acc0[8], acc1[8];
        #pragma unroll
        for (int nf = 0; nf < 8; ++nf) { acc0[nf] = z; acc1[nf] = z; }

        const f16x8* us = (const f16x8*)u_s;
        const f16x8* vs = (const f16x8*)v_s;
        const f16x8* wf = (const f16x8*)w_s;

        #pragma unroll
        for (int kk = 0; kk < 4; ++kk) {
            int kc  = kk * 4 + lhi;
            int scI = il * 16 + (kc ^ il);          // il&7 == il
            int scJ = (8 + jl) * 16 + (kc ^ jl);    // (8+jl)&7 == jl

            f16x8 uIv = us[scI];
            f16x8 vIv = vs[scI];
            f16x8 uJv = us[scJ];
            f16x8 vJv = vs[scJ];

            f16x8 s0 = uIv + vJv;
            f16x8 s1 = uJv + vIv;
            f16x8 h0, h1;
            #pragma unroll
            for (int e = 0; e < 8; ++e) {
                h0[e] = s0[e] < (_Float16)0 ? (_Float16)0 : s0[e];
                h1[e] = s1[e] < (_Float16)0 ? (_Float16)0 : s1[e];
            }

            #pragma unroll
            for (int nf = 0; nf < 8; ++nf) {
                f16x8 w = wf[(kk * 8 + nf) * 64 + lane];
                acc0[nf] = __builtin_amdgcn_mfma_f32_16x16x32_f16(
                    w, h0, acc0[nf], 0, 0, 0);
                acc1[nf] = __builtin_amdgcn_mfma_f32_16x16x32_f16(
                    w, h1, acc1[nf], 0, 0, 0);
            }
        }

        int Ig = I * 8 + il;
        int Jg = J * 8 + jl;
        float* p1 = out + ((size_t)b * 4096 + Ig * 64 + Jg) * 128 + lhi * 4;
        float* p2 = out + ((size_t)b * 4096 + Jg * 64 + Ig) * 128 + lhi * 4;
        bool mirror = (I != J);
        #pragma unroll
        for (int nf = 0; nf < 8; ++nf) {
            f32x4 bias = *(const f32x4*)(b1g + nf * 16 + lhi * 4);
            f32x4 val;
            #pragma unroll
            for (int e = 0; e < 4; ++e)
                val[e] = fmaxf(acc0[nf][e] + bias[e], 0.f) +
                         fmaxf(acc1[nf][e] + bias[e], 0.f);
            *(f32x4*)(p1 + nf * 16) = val;
            if (mirror)
                *(f32x4*)(p2 + nf * 16) = val;
        }
    }
}

extern "C" void kernel_launch(void* const* d_in, const int* in_sizes, int n_in,
                              void* d_out, int out_size, void* d_ws, size_t ws_size,
                              hipStream_t stream)
{
    (void)in_sizes; (void)n_in; (void)out_size; (void)ws_size;
    const float* x  = (const float*)d_in[0];
    const float* W0 = (const float*)d_in[1];
    const float* b0 = (const float*)d_in[2];
    const float* W1 = (const float*)d_in[3];
    const float* b1 = (const float*)d_in[4];
    float* out = (float*)d_out;

    _Float16* u   = (_Float16*)d_ws;                       // 0.5 MB
    _Float16* v   = u + (size_t)NB * NA * NC;              // 0.5 MB
    _Float16* w1f = v + (size_t)NB * NA * NC;              // 32 KB

    prep_kernel<<<520, 256, 0, stream>>>(x, W0, b0, W1, u, v, w1f);
    pair_mlp_kernel<<<576, 256, 0, stream>>>(b1, u, v, w1f, out);
}

// Round 17
// 28.021 us; speedup vs baseline: 1.4650x; 1.4182x over previous
//
#include <hip/hip_runtime.h>
#include <hip/hip_bf16.h>

typedef float    f32x4 __attribute__((ext_vector_type(4)));
typedef _Float16 f16x4 __attribute__((ext_vector_type(4)));
typedef _Float16 f16x8 __attribute__((ext_vector_type(8)));
typedef unsigned int   u32x4 __attribute__((ext_vector_type(4)));

#define NB 32
#define NA 64
#define NF 128
#define NC 128

// ---------------------------------------------------------------------------
// prep (R13/R14, measured ~3.8 us incl. boundary):
// blocks 0..511: u/v via latency-parallel f16 MFMA (task = (b, half, nq),
// 8 scalar W0 loads/thread, 4KB LDS, 4 MFMAs/wave).
// blocks 512..519: w1f = W1 in MFMA A-fragment order.
// ---------------------------------------------------------------------------
__global__ __launch_bounds__(256) void prep_kernel(
    const float* __restrict__ x, const float* __restrict__ W0,
    const float* __restrict__ b0, const float* __restrict__ W1,
    _Float16* __restrict__ u, _Float16* __restrict__ v,
    _Float16* __restrict__ w1f)
{
    int blk = blockIdx.x, tid = threadIdx.x;
    int lane = tid & 63, wave = tid >> 6;
    int llo = lane & 15, lhi = lane >> 4;

    if (blk < 512) {
        __shared__ __align__(16) _Float16 w0l[4 * 64 * 8];   // 4 KB frag-major
        int b = blk >> 4, half = (blk >> 3) & 1, nq = blk & 7;

        const float* xrow = x + ((size_t)b * NA + wave * 16 + llo) * NF;
        f16x8 xf[4];
        #pragma unroll
        for (int kk = 0; kk < 4; ++kk) {
            f32x4 a0 = *(const f32x4*)(xrow + kk * 32 + lhi * 8);
            f32x4 a1 = *(const f32x4*)(xrow + kk * 32 + lhi * 8 + 4);
            #pragma unroll
            for (int e = 0; e < 4; ++e) {
                xf[kk][e]     = (_Float16)a0[e];
                xf[kk][e + 4] = (_Float16)a1[e];
            }
        }

        {
            int kk = tid >> 6, ln = tid & 63;
            int k0 = half * 128 + kk * 32 + (ln >> 4) * 8;
            int c  = nq * 16 + (ln & 15);
            f16x8 o;
            #pragma unroll
            for (int e = 0; e < 8; ++e)
                o[e] = (_Float16)W0[(size_t)(k0 + e) * NC + c];
            *(f16x8*)(w0l + (size_t)tid * 8) = o;
        }
        __syncthreads();

        f32x4 acc = {0.f, 0.f, 0.f, 0.f};
        #pragma unroll
        for (int kk = 0; kk < 4; ++kk) {
            f16x8 bw = *(const f16x8*)(w0l + (size_t)((kk * 64 + lane)) * 8);
            acc = __builtin_amdgcn_mfma_f32_16x16x32_f16(xf[kk], bw, acc, 0, 0, 0);
        }

        _Float16* dst = half ? v : u;
        int c = nq * 16 + llo;
        float bb = half ? b0[c] : 0.f;
        #pragma unroll
        for (int q = 0; q < 4; ++q) {
            int atom = wave * 16 + lhi * 4 + q;
            dst[((size_t)b * NA + atom) * NC + c] = (_Float16)(acc[q] + bb);
        }
    } else {
        int fl   = (blk - 512) * 256 + tid;   // 0..2047
        int ln   = fl & 63;
        int frag = fl >> 6;                   // kk*8+nf
        int kk = frag >> 3, nf = frag & 7;
        int k0 = kk * 32 + (ln >> 4) * 8;
        int n  = nf * 16 + (ln & 15);
        f16x8 o;
        #pragma unroll
        for (int e = 0; e < 8; ++e)
            o[e] = (_Float16)W1[(size_t)(k0 + e) * NC + n];
        *(f16x8*)(w1f + (size_t)fl * 8) = o;
    }
}

// ---------------------------------------------------------------------------
// main (R14, measured best ~17.5 us): block = (batch b, unordered 8x8 atom
// tile pair (I<=J)), 1152 blocks x 256 thr, 4 blocks/CU. fp16 u/v tiles
// XOR-swizzled; W1 frag-order in LDS; mfma_f32_16x16x32_f16; mirror stores.
// ---------------------------------------------------------------------------
__global__ __launch_bounds__(256, 4) void pair_mlp_kernel(
    const float* __restrict__ b1g, const _Float16* __restrict__ u,
    const _Float16* __restrict__ v, const _Float16* __restrict__ w1f,
    float* __restrict__ out)
{
    __shared__ __align__(16) _Float16 u_s[16 * 128];    // 4 KB
    __shared__ __align__(16) _Float16 v_s[16 * 128];    // 4 KB
    __shared__ __align__(16) _Float16 w_s[32 * 64 * 8]; // 32 KB frag-major

    int blk = blockIdx.x;
    int b = blk / 36;
    int t = blk % 36;
    int I = 0;
    while (t >= 8 - I) { t -= 8 - I; ++I; }
    int J = I + t;

    int tid = threadIdx.x;

    {
        int row = tid >> 4;            // 0..15
        int c   = tid & 15;            // 16B chunk within 256B row
        int ga  = b * NA + ((row < 8) ? (I * 8 + row) : (J * 8 + (row & 7)));
        int sc  = row * 16 + (c ^ (row & 7));
        ((u32x4*)u_s)[sc] = ((const u32x4*)(u + (size_t)ga * NC))[c];
        ((u32x4*)v_s)[sc] = ((const u32x4*)(v + (size_t)ga * NC))[c];
    }
    #pragma unroll
    for (int p = 0; p < 8; ++p)
        ((u32x4*)w_s)[p * 256 + tid] = ((const u32x4*)w1f)[p * 256 + tid];
    __syncthreads();

    int wave = tid >> 6;
    int lane = tid & 63;
    int llo  = lane & 15;
    int lhi  = lane >> 4;
    int r    = wave * 16 + llo;
    int il   = r >> 3;            // 0..7
    int jl   = r & 7;             // 0..7

    f32x4 acc0[8], acc1[8];
    f32x4 z = {0.f, 0.f, 0.f, 0.f};
    #pragma unroll
    for (int nf = 0; nf < 8; ++nf) { acc0[nf] = z; acc1[nf] = z; }

    const f16x8* us = (const f16x8*)u_s;
    const f16x8* vs = (const f16x8*)v_s;
    const f16x8* wf = (const f16x8*)w_s;

    #pragma unroll
    for (int kk = 0; kk < 4; ++kk) {
        int kc  = kk * 4 + lhi;
        int scI = il * 16 + (kc ^ il);          // il&7 == il
        int scJ = (8 + jl) * 16 + (kc ^ jl);    // (8+jl)&7 == jl

        f16x8 uIv = us[scI];
        f16x8 vIv = vs[scI];
        f16x8 uJv = us[scJ];
        f16x8 vJv = vs[scJ];

        f16x8 s0 = uIv + vJv;
        f16x8 s1 = uJv + vIv;
        f16x8 h0, h1;
        #pragma unroll
        for (int e = 0; e < 8; ++e) {
            h0[e] = s0[e] < (_Float16)0 ? (_Float16)0 : s0[e];
            h1[e] = s1[e] < (_Float16)0 ? (_Float16)0 : s1[e];
        }

        #pragma unroll
        for (int nf = 0; nf < 8; ++nf) {
            f16x8 w = wf[(kk * 8 + nf) * 64 + lane];
            acc0[nf] = __builtin_amdgcn_mfma_f32_16x16x32_f16(w, h0, acc0[nf], 0, 0, 0);
            acc1[nf] = __builtin_amdgcn_mfma_f32_16x16x32_f16(w, h1, acc1[nf], 0, 0, 0);
        }
    }

    int Ig = I * 8 + il;
    int Jg = J * 8 + jl;
    float* p1 = out + ((size_t)b * 4096 + Ig * 64 + Jg) * 128 + lhi * 4;
    float* p2 = out + ((size_t)b * 4096 + Jg * 64 + Ig) * 128 + lhi * 4;
    bool mirror = (I != J);
    #pragma unroll
    for (int nf = 0; nf < 8; ++nf) {
        f32x4 bias = *(const f32x4*)(b1g + nf * 16 + lhi * 4);
        f32x4 val;
        #pragma unroll
        for (int e = 0; e < 4; ++e)
            val[e] = fmaxf(acc0[nf][e] + bias[e], 0.f) +
                     fmaxf(acc1[nf][e] + bias[e], 0.f);
        *(f32x4*)(p1 + nf * 16) = val;
        if (mirror)
            *(f32x4*)(p2 + nf * 16) = val;
    }
}

extern "C" void kernel_launch(void* const* d_in, const int* in_sizes, int n_in,
                              void* d_out, int out_size, void* d_ws, size_t ws_size,
                              hipStream_t stream)
{
    (void)in_sizes; (void)n_in; (void)out_size; (void)ws_size;
    const float* x  = (const float*)d_in[0];
    const float* W0 = (const float*)d_in[1];
    const float* b0 = (const float*)d_in[2];
    const float* W1 = (const float*)d_in[3];
    const float* b1 = (const float*)d_in[4];
    float* out = (float*)d_out;

    _Float16* u   = (_Float16*)d_ws;                       // 0.5 MB
    _Float16* v   = u + (size_t)NB * NA * NC;              // 0.5 MB
    _Float16* w1f = v + (size_t)NB * NA * NC;              // 32 KB

    prep_kernel<<<520, 256, 0, stream>>>(x, W0, b0, W1, u, v, w1f);
    pair_mlp_kernel<<<32 * 36, 256, 0, stream>>>(b1, u, v, w1f, out);
}